// Round 1
// baseline (273.884 us; speedup 1.0000x reference)
//
#include <hip/hip_runtime.h>

typedef __bf16 bf16x8 __attribute__((ext_vector_type(8)));
typedef float f32x4 __attribute__((ext_vector_type(4)));

__device__ __forceinline__ unsigned short f2bf(float f) {
  union { float f; unsigned u; } v; v.f = f;
  unsigned u = v.u;
  unsigned r = (u + 0x7fffu + ((u >> 16) & 1u)) >> 16;  // RNE
  return (unsigned short)r;
}

__device__ __forceinline__ void gload_lds16(const void* g, void* l) {
  __builtin_amdgcn_global_load_lds(
      (const __attribute__((address_space(1))) unsigned int*)g,
      (__attribute__((address_space(3))) unsigned int*)l, 16, 0, 0);
}

// ---------------- conversion kernels ----------------
__global__ void cvt_f32_bf16(const float* __restrict__ src,
                             unsigned short* __restrict__ dst, int n4) {
  int i = blockIdx.x * blockDim.x + threadIdx.x;
  if (i < n4) {
    f32x4 v = ((const f32x4*)src)[i];
    union { unsigned short s[4]; unsigned long long u; } o;
    o.s[0] = f2bf(v[0]); o.s[1] = f2bf(v[1]);
    o.s[2] = f2bf(v[2]); o.s[3] = f2bf(v[3]);
    ((unsigned long long*)dst)[i] = o.u;
  }
}

// w2: (64, 2048) f32  ->  w2t: (2048, 64) bf16
__global__ void pack_w2t(const float* __restrict__ w2,
                         unsigned short* __restrict__ w2t) {
  int idx = blockIdx.x * blockDim.x + threadIdx.x;  // 0..131071
  int j = idx >> 6, d = idx & 63;
  w2t[idx] = f2bf(w2[d * 2048 + j]);
}

// ---------------- GEMM: C = epilogue(A @ Bt^T + bias) ----------------
// A: (M,K) bf16 K-major; Bt: (N,K) bf16 K-major; C: (M,N)
// EPI 0: bias per col + relu, bf16 out
// EPI 1: bias per row,        bf16 out
// EPI 2: bias per col,        f32 out
template <int EPI>
__global__ __launch_bounds__(256) void gemm_bt(
    const unsigned short* __restrict__ A, const unsigned short* __restrict__ Bt,
    const float* __restrict__ bias, void* __restrict__ Cv,
    int M, int N, int K) {
  __shared__ unsigned short As[128 * 64];
  __shared__ unsigned short Bs[128 * 64];
  const int tid = threadIdx.x;
  const int wv = tid >> 6, ln = tid & 63;
  const int quad = ln >> 4, lq = ln & 15;
  const int wr = wv >> 1, wc = wv & 1;
  const int tileM = blockIdx.y * 128, tileN = blockIdx.x * 128;
  const int rowL = ln >> 3;
  const int kc = (ln & 7) * 8;

  f32x4 acc[4][4];
  const f32x4 zf = {0.f, 0.f, 0.f, 0.f};
#pragma unroll
  for (int i = 0; i < 4; ++i)
#pragma unroll
    for (int j = 0; j < 4; ++j) acc[i][j] = zf;

  for (int k0 = 0; k0 < K; k0 += 64) {
    __syncthreads();
#pragma unroll
    for (int l = 0; l < 4; ++l) {
      int row = l * 32 + wv * 8 + rowL;
      gload_lds16(A + (tileM + row) * K + k0 + kc, &As[l * 2048 + wv * 512]);
      gload_lds16(Bt + (tileN + row) * K + k0 + kc, &Bs[l * 2048 + wv * 512]);
    }
    __syncthreads();
#pragma unroll
    for (int kk = 0; kk < 2; ++kk) {
      bf16x8 af[4], bfr[4];
#pragma unroll
      for (int mi = 0; mi < 4; ++mi)
        af[mi] = *(const bf16x8*)&As[(wr * 64 + mi * 16 + lq) * 64 + kk * 32 + quad * 8];
#pragma unroll
      for (int ni = 0; ni < 4; ++ni)
        bfr[ni] = *(const bf16x8*)&Bs[(wc * 64 + ni * 16 + lq) * 64 + kk * 32 + quad * 8];
#pragma unroll
      for (int mi = 0; mi < 4; ++mi)
#pragma unroll
        for (int ni = 0; ni < 4; ++ni)
          acc[mi][ni] = __builtin_amdgcn_mfma_f32_16x16x32_bf16(af[mi], bfr[ni], acc[mi][ni], 0, 0, 0);
    }
  }

#pragma unroll
  for (int mi = 0; mi < 4; ++mi) {
#pragma unroll
    for (int ni = 0; ni < 4; ++ni) {
      int col = tileN + wc * 64 + ni * 16 + lq;
#pragma unroll
      for (int rg = 0; rg < 4; ++rg) {
        int row = tileM + wr * 64 + mi * 16 + quad * 4 + rg;
        float v = acc[mi][ni][rg];
        if (EPI == 0) {
          v += bias[col];
          v = v > 0.f ? v : 0.f;
          ((unsigned short*)Cv)[row * N + col] = f2bf(v);
        } else if (EPI == 1) {
          v += bias[row];
          ((unsigned short*)Cv)[row * N + col] = f2bf(v);
        } else {
          v += bias[col];
          ((float*)Cv)[row * N + col] = v;
        }
      }
    }
  }
}

// ---------------- fused synthesizer attention ----------------
// r:   (B*T, C) bf16        (row t, channel h*64+d)
// w2t: (2048, 64) bf16      (row j, col d)
// vt:  (C, B*T) bf16        (row h*64+d, col b*2048+t)
// y:   (B*T, C) bf16 out
// grid: (T/64 = 32, B*NH = 32), block 256 (4 waves, 16 t-rows each)
__global__ __launch_bounds__(256) void attn(
    const unsigned short* __restrict__ r, const unsigned short* __restrict__ w2t,
    const unsigned short* __restrict__ vt, const float* __restrict__ b2,
    unsigned short* __restrict__ y) {
  __shared__ unsigned short Rs[64 * 64];
  __shared__ unsigned short W2s[64 * 64];
  __shared__ unsigned short Vs[64 * 64];
  __shared__ unsigned short Ps[4][16 * 64];

  const int tid = threadIdx.x;
  const int wv = tid >> 6, ln = tid & 63;
  const int quad = ln >> 4, lq = ln & 15;
  const int tt = blockIdx.x, bh = blockIdx.y;
  const int b = bh >> 4, h = bh & 15;
  const int t0 = tt * 64;
  const int rowL = ln >> 3;
  const int kc = (ln & 7) * 8;

  // stage R tile once (64 rows x 64 d)
#pragma unroll
  for (int l = 0; l < 2; ++l) {
    int row = l * 32 + wv * 8 + rowL;
    gload_lds16(r + (b * 2048 + t0 + row) * 1024 + h * 64 + kc,
                &Rs[l * 2048 + wv * 512]);
  }

  f32x4 accY[4];
  float accL[4];
  const f32x4 zf = {0.f, 0.f, 0.f, 0.f};
#pragma unroll
  for (int i = 0; i < 4; ++i) { accY[i] = zf; accL[i] = 0.f; }

  for (int jt = 0; jt <= tt; ++jt) {
    int j0 = jt * 64;
    __syncthreads();  // previous-iter readers done; also drains R staging on iter 0
#pragma unroll
    for (int l = 0; l < 2; ++l) {
      int row = l * 32 + wv * 8 + rowL;
      gload_lds16(w2t + (j0 + row) * 64 + kc, &W2s[l * 2048 + wv * 512]);
      gload_lds16(vt + (h * 64 + row) * 4096 + b * 2048 + j0 + kc,
                  &Vs[l * 2048 + wv * 512]);
    }
    __syncthreads();

    // S = R_wave(16x64) @ W2tile^T  -> s[ni]: rows quad*4+rg (t), col lq (j)
    f32x4 s[4];
#pragma unroll
    for (int ni = 0; ni < 4; ++ni) s[ni] = zf;
#pragma unroll
    for (int kk = 0; kk < 2; ++kk) {
      bf16x8 a = *(const bf16x8*)&Rs[(wv * 16 + lq) * 64 + kk * 32 + quad * 8];
#pragma unroll
      for (int ni = 0; ni < 4; ++ni) {
        bf16x8 bb = *(const bf16x8*)&W2s[(ni * 16 + lq) * 64 + kk * 32 + quad * 8];
        s[ni] = __builtin_amdgcn_mfma_f32_16x16x32_bf16(a, bb, s[ni], 0, 0, 0);
      }
    }

    // mask + exp (logits tiny: no max subtraction needed), write P (A-layout via LDS)
#pragma unroll
    for (int ni = 0; ni < 4; ++ni) {
      int j = j0 + ni * 16 + lq;
      float bj = b2[j];
#pragma unroll
      for (int rg = 0; rg < 4; ++rg) {
        int t = t0 + wv * 16 + quad * 4 + rg;
        float p = (j <= t) ? __expf(s[ni][rg] + bj) : 0.f;
        accL[rg] += p;
        Ps[wv][(quad * 4 + rg) * 64 + ni * 16 + lq] = f2bf(p);
      }
    }
    __syncthreads();

    // Y += P(16x64) @ V(64x64)
#pragma unroll
    for (int kk = 0; kk < 2; ++kk) {
      bf16x8 a = *(const bf16x8*)&Ps[wv][lq * 64 + kk * 32 + quad * 8];
#pragma unroll
      for (int nd = 0; nd < 4; ++nd) {
        bf16x8 bb = *(const bf16x8*)&Vs[(nd * 16 + lq) * 64 + kk * 32 + quad * 8];
        accY[nd] = __builtin_amdgcn_mfma_f32_16x16x32_bf16(a, bb, accY[nd], 0, 0, 0);
      }
    }
  }

  // reduce row-sums across the 16 lanes of each quad (cols)
#pragma unroll
  for (int rg = 0; rg < 4; ++rg) {
    float v = accL[rg];
    v += __shfl_xor(v, 1);
    v += __shfl_xor(v, 2);
    v += __shfl_xor(v, 4);
    v += __shfl_xor(v, 8);
    accL[rg] = v;
  }

#pragma unroll
  for (int nd = 0; nd < 4; ++nd) {
#pragma unroll
    for (int rg = 0; rg < 4; ++rg) {
      int t = t0 + wv * 16 + quad * 4 + rg;
      int d = nd * 16 + lq;
      y[(b * 2048 + t) * 1024 + h * 64 + d] = f2bf(accY[nd][rg] / accL[rg]);
    }
  }
}

// ---------------- launch ----------------
extern "C" void kernel_launch(void* const* d_in, const int* in_sizes, int n_in,
                              void* d_out, int out_size, void* d_ws, size_t ws_size,
                              hipStream_t stream) {
  const float* x  = (const float*)d_in[0];
  const float* W1 = (const float*)d_in[1];
  const float* b1 = (const float*)d_in[2];
  const float* w2 = (const float*)d_in[3];
  const float* b2 = (const float*)d_in[4];
  const float* Wv = (const float*)d_in[5];
  const float* bv = (const float*)d_in[6];
  const float* Wp = (const float*)d_in[7];
  const float* bp = (const float*)d_in[8];

  unsigned short* ws  = (unsigned short*)d_ws;
  unsigned short* xb  = ws;                 // 4096x1024
  unsigned short* W1b = ws + 4194304;       // 1024x1024
  unsigned short* Wvb = ws + 5242880;       // 1024x1024
  unsigned short* Wpb = ws + 6291456;       // 1024x1024
  unsigned short* w2t = ws + 7340032;       // 2048x64
  unsigned short* rb  = ws + 7471104;       // 4096x1024
  unsigned short* vt  = ws + 11665408;      // 1024x4096 (transposed v)
  unsigned short* yb  = ws + 15859712;      // 4096x1024

  cvt_f32_bf16<<<4096, 256, 0, stream>>>(x, xb, 1048576);
  cvt_f32_bf16<<<1024, 256, 0, stream>>>(W1, W1b, 262144);
  cvt_f32_bf16<<<1024, 256, 0, stream>>>(Wv, Wvb, 262144);
  cvt_f32_bf16<<<1024, 256, 0, stream>>>(Wp, Wpb, 262144);
  pack_w2t<<<512, 256, 0, stream>>>(w2, w2t);

  // r = relu(x @ W1^T + b1)   (M=4096, N=1024, K=1024)
  gemm_bt<0><<<dim3(8, 32), 256, 0, stream>>>(xb, W1b, b1, rb, 4096, 1024, 1024);
  // vt = (x @ Wv^T + bv)^T = Wv @ x^T + bv[row]   (M=1024, N=4096, K=1024)
  gemm_bt<1><<<dim3(32, 8), 256, 0, stream>>>(Wvb, xb, bv, vt, 1024, 4096, 1024);
  // fused synthesizer attention -> y (bf16)
  attn<<<dim3(32, 32), 256, 0, stream>>>(rb, w2t, vt, b2, yb);
  // out = y @ Wp^T + bp  (f32)
  gemm_bt<2><<<dim3(8, 32), 256, 0, stream>>>(yb, Wpb, bp, d_out, 4096, 1024, 1024);
}

// Round 3
// 224.308 us; speedup vs baseline: 1.2210x; 1.2210x over previous
//
#include <hip/hip_runtime.h>

typedef __bf16 bf16x8 __attribute__((ext_vector_type(8)));
typedef float f32x4 __attribute__((ext_vector_type(4)));

__device__ __forceinline__ unsigned short f2bf(float f) {
  union { float f; unsigned u; } v; v.f = f;
  unsigned u = v.u;
  return (unsigned short)((u + 0x7fffu + ((u >> 16) & 1u)) >> 16);  // RNE
}
__device__ __forceinline__ unsigned short f2bf_fast(float f) {
  union { float f; unsigned u; } v; v.f = f;
  return (unsigned short)((v.u + 0x8000u) >> 16);  // round-half-up, for P only
}
__device__ __forceinline__ void gload_lds16(const void* g, void* l) {
  __builtin_amdgcn_global_load_lds(
      (const __attribute__((address_space(1))) unsigned int*)g,
      (__attribute__((address_space(3))) unsigned int*)l, 16, 0, 0);
}
__device__ __forceinline__ void cvt4(const float* __restrict__ s,
                                     unsigned short* __restrict__ d, int u) {
  f32x4 v = ((const f32x4*)s)[u];
  union { unsigned short s[4]; unsigned long long u; } o;
  o.s[0] = f2bf(v[0]); o.s[1] = f2bf(v[1]); o.s[2] = f2bf(v[2]); o.s[3] = f2bf(v[3]);
  ((unsigned long long*)d)[u] = o.u;
}

// ---------------- prep: all f32->bf16 conversions + zero-init, one launch ----
// unit budget: x 1048576 | W1 262144 | Wv 262144 | Wp 262144 | zeroA 1048576
//            | zeroB 16384 | w2t 32768  => total 2932736 units, 11456 blocks
__global__ void prep(const float* __restrict__ x, const float* __restrict__ W1,
                     const float* __restrict__ Wv, const float* __restrict__ Wp,
                     const float* __restrict__ w2, unsigned short* __restrict__ xb,
                     unsigned short* __restrict__ W1b, unsigned short* __restrict__ Wvb,
                     unsigned short* __restrict__ Wpb, unsigned short* __restrict__ w2t,
                     float* __restrict__ zeroA, float* __restrict__ zeroB) {
  int u = blockIdx.x * 256 + threadIdx.x;
  const f32x4 zf = {0.f, 0.f, 0.f, 0.f};
  if (u < 1048576) { cvt4(x, xb, u); return; }       // x: 2*2048*1024 f32
  u -= 1048576;
  if (u < 262144) { cvt4(W1, W1b, u); return; }
  u -= 262144;
  if (u < 262144) { cvt4(Wv, Wvb, u); return; }
  u -= 262144;
  if (u < 262144) { cvt4(Wp, Wpb, u); return; }
  u -= 262144;
  if (u < 1048576) { ((f32x4*)zeroA)[u] = zf; return; }
  u -= 1048576;
  if (u < 16384) { ((f32x4*)zeroB)[u] = zf; return; }
  u -= 16384;
  // w2 (64,2048) f32 -> w2t (2048,64) bf16
  int j = u >> 4, d4 = (u & 15) * 4;
  union { unsigned short s[4]; unsigned long long x; } o;
#pragma unroll
  for (int i = 0; i < 4; ++i) o.s[i] = f2bf(w2[(d4 + i) * 2048 + j]);
  ((unsigned long long*)w2t)[u] = o.x;
}

// ---------------- merged r & vt GEMM (512 blocks, m97 structure) ------------
// id<256:  rb = relu(xb @ W1b^T + b1)   M=4096 N=1024
// id>=256: vt = Wvb @ xb^T + bv[row]    M=1024 N=4096
__global__ __launch_bounds__(256) void gemm_rv(
    const unsigned short* __restrict__ xb, const unsigned short* __restrict__ W1b,
    const unsigned short* __restrict__ Wvb, const float* __restrict__ b1,
    const float* __restrict__ bv, unsigned short* __restrict__ rb,
    unsigned short* __restrict__ vtb) {
  __shared__ unsigned short As[128 * 64];
  __shared__ unsigned short Bs[128 * 64];
  int id = blockIdx.x;
  const unsigned short *A, *Bt;
  const float* bias;
  unsigned short* C;
  int N, tileM, tileN, epi;
  if (id < 256) {
    A = xb; Bt = W1b; bias = b1; C = rb; N = 1024; epi = 0;
    tileN = (id & 7) * 128; tileM = (id >> 3) * 128;
  } else {
    id -= 256;
    A = Wvb; Bt = xb; bias = bv; C = vtb; N = 4096; epi = 1;
    tileN = (id & 31) * 128; tileM = (id >> 5) * 128;
  }
  const int tid = threadIdx.x;
  const int wv = tid >> 6, ln = tid & 63;
  const int quad = ln >> 4, lq = ln & 15;
  const int wr = wv >> 1, wc = wv & 1;
  const int rowL = ln >> 3, kc = (ln & 7) * 8;

  f32x4 acc[4][4];
  const f32x4 zf = {0.f, 0.f, 0.f, 0.f};
#pragma unroll
  for (int i = 0; i < 4; ++i)
#pragma unroll
    for (int j = 0; j < 4; ++j) acc[i][j] = zf;

  for (int k0 = 0; k0 < 1024; k0 += 64) {
    __syncthreads();
#pragma unroll
    for (int l = 0; l < 4; ++l) {
      int row = l * 32 + wv * 8 + rowL;
      gload_lds16(A + (tileM + row) * 1024 + k0 + kc, &As[l * 2048 + wv * 512]);
      gload_lds16(Bt + (tileN + row) * 1024 + k0 + kc, &Bs[l * 2048 + wv * 512]);
    }
    __syncthreads();
#pragma unroll
    for (int kk = 0; kk < 2; ++kk) {
      bf16x8 af[4], bfr[4];
#pragma unroll
      for (int mi = 0; mi < 4; ++mi)
        af[mi] = *(const bf16x8*)&As[(wr * 64 + mi * 16 + lq) * 64 + kk * 32 + quad * 8];
#pragma unroll
      for (int ni = 0; ni < 4; ++ni)
        bfr[ni] = *(const bf16x8*)&Bs[(wc * 64 + ni * 16 + lq) * 64 + kk * 32 + quad * 8];
#pragma unroll
      for (int mi = 0; mi < 4; ++mi)
#pragma unroll
        for (int ni = 0; ni < 4; ++ni)
          acc[mi][ni] = __builtin_amdgcn_mfma_f32_16x16x32_bf16(af[mi], bfr[ni], acc[mi][ni], 0, 0, 0);
    }
  }
#pragma unroll
  for (int mi = 0; mi < 4; ++mi)
#pragma unroll
    for (int ni = 0; ni < 4; ++ni) {
      int col = tileN + wc * 64 + ni * 16 + lq;
#pragma unroll
      for (int rg = 0; rg < 4; ++rg) {
        int row = tileM + wr * 64 + mi * 16 + quad * 4 + rg;
        float v = acc[mi][ni][rg];
        if (epi == 0) {
          v += bias[col];
          v = v > 0.f ? v : 0.f;
        } else {
          v += bias[row];
        }
        C[row * N + col] = f2bf(v);
      }
    }
}

// ---------------- final GEMM: d_out = yb @ Wp^T + bp (f32 out) --------------
__global__ __launch_bounds__(256) void gemm_p(
    const unsigned short* __restrict__ A, const unsigned short* __restrict__ Bt,
    const float* __restrict__ bias, float* __restrict__ C) {
  __shared__ unsigned short As[128 * 64];
  __shared__ unsigned short Bs[128 * 64];
  const int tid = threadIdx.x;
  const int wv = tid >> 6, ln = tid & 63;
  const int quad = ln >> 4, lq = ln & 15;
  const int wr = wv >> 1, wc = wv & 1;
  const int tileM = blockIdx.y * 128, tileN = blockIdx.x * 128;
  const int rowL = ln >> 3, kc = (ln & 7) * 8;

  f32x4 acc[4][4];
  const f32x4 zf = {0.f, 0.f, 0.f, 0.f};
#pragma unroll
  for (int i = 0; i < 4; ++i)
#pragma unroll
    for (int j = 0; j < 4; ++j) acc[i][j] = zf;

  for (int k0 = 0; k0 < 1024; k0 += 64) {
    __syncthreads();
#pragma unroll
    for (int l = 0; l < 4; ++l) {
      int row = l * 32 + wv * 8 + rowL;
      gload_lds16(A + (tileM + row) * 1024 + k0 + kc, &As[l * 2048 + wv * 512]);
      gload_lds16(Bt + (tileN + row) * 1024 + k0 + kc, &Bs[l * 2048 + wv * 512]);
    }
    __syncthreads();
#pragma unroll
    for (int kk = 0; kk < 2; ++kk) {
      bf16x8 af[4], bfr[4];
#pragma unroll
      for (int mi = 0; mi < 4; ++mi)
        af[mi] = *(const bf16x8*)&As[(wr * 64 + mi * 16 + lq) * 64 + kk * 32 + quad * 8];
#pragma unroll
      for (int ni = 0; ni < 4; ++ni)
        bfr[ni] = *(const bf16x8*)&Bs[(wc * 64 + ni * 16 + lq) * 64 + kk * 32 + quad * 8];
#pragma unroll
      for (int mi = 0; mi < 4; ++mi)
#pragma unroll
        for (int ni = 0; ni < 4; ++ni)
          acc[mi][ni] = __builtin_amdgcn_mfma_f32_16x16x32_bf16(af[mi], bfr[ni], acc[mi][ni], 0, 0, 0);
    }
  }
#pragma unroll
  for (int mi = 0; mi < 4; ++mi)
#pragma unroll
    for (int ni = 0; ni < 4; ++ni) {
      int col = tileN + wc * 64 + ni * 16 + lq;
#pragma unroll
      for (int rg = 0; rg < 4; ++rg) {
        int row = tileM + wr * 64 + mi * 16 + quad * 4 + rg;
        C[row * 1024 + col] = acc[mi][ni][rg] + bias[col];
      }
    }
}

// ---------------- fused synthesizer attention (balanced + split-j) ----------
// Pair t-tiles (p, 31-p): uniform 33 tile-units; split j-range in half ->
// 1024 uniform blocks. Partial sums atomically added into y32 (=d_out scratch)
// and Lsum; normalize pass divides. LDS = 40960B -> 4 blocks/CU.
__global__ __launch_bounds__(256, 4) void attn(
    const unsigned short* __restrict__ r, const unsigned short* __restrict__ w2t,
    const unsigned short* __restrict__ vt, const float* __restrict__ b2,
    float* __restrict__ y32, float* __restrict__ Lsum) {
  __shared__ unsigned short W2s[2][64 * 64];
  __shared__ unsigned short Vs[2][64 * 64];
  __shared__ unsigned short Ps[4][16 * 64];

  const int tid = threadIdx.x;
  const int wv = tid >> 6, ln = tid & 63;
  const int quad = ln >> 4, lq = ln & 15;
  const int pr = blockIdx.x >> 1, half = blockIdx.x & 1;
  const int bh = blockIdx.y, b = bh >> 4, h = bh & 15;
  const int ta = pr, tb = 31 - pr;
  const int sp = (ta >= 8) ? 8 : 16 - ta;          // balanced split point
  const int jlo = half ? sp : 0, jhi = half ? tb : sp - 1;
  const int rowL = ln >> 3, kc = (ln & 7) * 8;
  const int t0a = ta * 64, t0b = tb * 64;

  // R A-fragments for both t-tiles, straight from global (L2/L3-hot)
  bf16x8 ra[2][2];
  {
    const unsigned short* base = r + (b * 2048 + wv * 16 + lq) * 1024 + h * 64 + quad * 8;
    ra[0][0] = *(const bf16x8*)(base + t0a * 1024);
    ra[0][1] = *(const bf16x8*)(base + t0a * 1024 + 32);
    ra[1][0] = *(const bf16x8*)(base + t0b * 1024);
    ra[1][1] = *(const bf16x8*)(base + t0b * 1024 + 32);
  }

  f32x4 accY[2][4];
  f32x4 accL[2];
  const f32x4 zf = {0.f, 0.f, 0.f, 0.f};
#pragma unroll
  for (int s = 0; s < 2; ++s) {
    accL[s] = zf;
#pragma unroll
    for (int nd = 0; nd < 4; ++nd) accY[s][nd] = zf;
  }
  bf16x8 vones;
#pragma unroll
  for (int i = 0; i < 8; ++i) vones[i] = (__bf16)1.0f;

  auto stage = [&](int jt, int bi) {
    int j0 = jt * 64;
#pragma unroll
    for (int l = 0; l < 2; ++l) {
      int row = l * 32 + wv * 8 + rowL;
      gload_lds16(w2t + (j0 + row) * 64 + kc, &W2s[bi][l * 2048 + wv * 512]);
      gload_lds16(vt + (h * 64 + row) * 4096 + b * 2048 + j0 + kc,
                  &Vs[bi][l * 2048 + wv * 512]);
    }
  };

  stage(jlo, 0);
  for (int jt = jlo; jt <= jhi; ++jt) {
    const int cb = (jt - jlo) & 1;
    __syncthreads();                 // staging(jt) landed; prev readers of other buf done
    if (jt < jhi) stage(jt + 1, cb ^ 1);  // prefetch overlaps compute below
    const int j0 = jt * 64;

#define TILE(S, T0, TT)                                                         \
    {                                                                           \
      f32x4 sv[4] = {zf, zf, zf, zf};                                           \
      _Pragma("unroll") for (int kk = 0; kk < 2; ++kk) {                        \
        _Pragma("unroll") for (int ni = 0; ni < 4; ++ni) {                      \
          bf16x8 bb = *(const bf16x8*)&W2s[cb][(ni * 16 + lq) * 64 + kk * 32 + quad * 8]; \
          sv[ni] = __builtin_amdgcn_mfma_f32_16x16x32_bf16(ra[S][kk], bb, sv[ni], 0, 0, 0); \
        }                                                                       \
      }                                                                         \
      const bool diag = (jt == (TT));                                           \
      _Pragma("unroll") for (int ni = 0; ni < 4; ++ni) {                        \
        int j = j0 + ni * 16 + lq;                                              \
        float bj = b2[j];                                                       \
        _Pragma("unroll") for (int rg = 0; rg < 4; ++rg) {                      \
          float p = __expf(sv[ni][rg] + bj);                                    \
          if (diag) {                                                           \
            int t = (T0) + wv * 16 + quad * 4 + rg;                             \
            p = (j <= t) ? p : 0.f;                                             \
          }                                                                     \
          Ps[wv][(quad * 4 + rg) * 64 + ni * 16 + lq] = f2bf_fast(p);           \
        }                                                                       \
      }                                                                         \
      _Pragma("unroll") for (int kk = 0; kk < 2; ++kk) {                        \
        bf16x8 pa = *(const bf16x8*)&Ps[wv][lq * 64 + kk * 32 + quad * 8];      \
        _Pragma("unroll") for (int nd = 0; nd < 4; ++nd) {                      \
          bf16x8 bb = *(const bf16x8*)&Vs[cb][(nd * 16 + lq) * 64 + kk * 32 + quad * 8]; \
          accY[S][nd] = __builtin_amdgcn_mfma_f32_16x16x32_bf16(pa, bb, accY[S][nd], 0, 0, 0); \
        }                                                                       \
        accL[S] = __builtin_amdgcn_mfma_f32_16x16x32_bf16(pa, vones, accL[S], 0, 0, 0); \
      }                                                                         \
    }

    if (jt <= ta) TILE(0, t0a, ta);
    TILE(1, t0b, tb);
#undef TILE
  }

#pragma unroll
  for (int s = 0; s < 2; ++s) {
    if (!(s == 0 && jlo > ta)) {
      const int t0s = s ? t0b : t0a;
#pragma unroll
      for (int nd = 0; nd < 4; ++nd)
#pragma unroll
        for (int rg = 0; rg < 4; ++rg) {
          int t = t0s + wv * 16 + quad * 4 + rg;
          atomicAdd(&y32[(b * 2048 + t) * 1024 + h * 64 + nd * 16 + lq], accY[s][nd][rg]);
        }
      if (lq == 0) {
#pragma unroll
        for (int rg = 0; rg < 4; ++rg) {
          int t = t0s + wv * 16 + quad * 4 + rg;
          atomicAdd(&Lsum[(b * 2048 + t) * 16 + h], accL[s][rg]);
        }
      }
    }
  }
}

// ---------------- normalize: yb = bf16(y32 / Lsum) --------------------------
__global__ void normfin(const float* __restrict__ y32, const float* __restrict__ Lsum,
                        unsigned short* __restrict__ yb) {
  int u = blockIdx.x * 256 + threadIdx.x;   // 1048576 units of f32x4
  int tg = u >> 8, h = (u & 255) >> 4;      // c = (u&255)*4; h = c>>6 = (u&255)>>4
  float inv = 1.0f / Lsum[tg * 16 + h];
  f32x4 v = ((const f32x4*)y32)[u];
  union { unsigned short s[4]; unsigned long long x; } o;
  o.s[0] = f2bf(v[0] * inv); o.s[1] = f2bf(v[1] * inv);
  o.s[2] = f2bf(v[2] * inv); o.s[3] = f2bf(v[3] * inv);
  ((unsigned long long*)yb)[u] = o.x;
}

// ---------------- launch ----------------
extern "C" void kernel_launch(void* const* d_in, const int* in_sizes, int n_in,
                              void* d_out, int out_size, void* d_ws, size_t ws_size,
                              hipStream_t stream) {
  const float* x  = (const float*)d_in[0];
  const float* W1 = (const float*)d_in[1];
  const float* b1 = (const float*)d_in[2];
  const float* w2 = (const float*)d_in[3];
  const float* b2 = (const float*)d_in[4];
  const float* Wv = (const float*)d_in[5];
  const float* bv = (const float*)d_in[6];
  const float* Wp = (const float*)d_in[7];
  const float* bp = (const float*)d_in[8];

  unsigned short* ws  = (unsigned short*)d_ws;
  unsigned short* xb  = ws;                 // 4096x1024 bf16
  unsigned short* W1b = ws + 4194304;       // 1024x1024
  unsigned short* Wvb = ws + 5242880;       // 1024x1024
  unsigned short* Wpb = ws + 6291456;       // 1024x1024
  unsigned short* w2t = ws + 7340032;       // 2048x64
  unsigned short* rb  = ws + 7471104;       // 4096x1024
  unsigned short* vt  = ws + 11665408;      // 1024x4096
  unsigned short* yb  = ws + 15859712;      // 4096x1024
  float* Lsum = (float*)(ws + 20054016);    // 4096x16 f32
  float* y32  = (float*)d_out;              // 16MB f32 scratch, overwritten by gemm_p

  prep<<<11456, 256, 0, stream>>>(x, W1, Wv, Wp, w2, xb, W1b, Wvb, Wpb, w2t, y32, Lsum);
  gemm_rv<<<512, 256, 0, stream>>>(xb, W1b, Wvb, b1, bv, rb, vt);
  attn<<<dim3(32, 32), 256, 0, stream>>>(rb, w2t, vt, b2, y32, Lsum);
  normfin<<<4096, 256, 0, stream>>>(y32, Lsum, yb);
  gemm_p<<<dim3(8, 32), 256, 0, stream>>>(yb, Wpb, bp, (float*)d_out);
}

// Round 4
// 214.233 us; speedup vs baseline: 1.2784x; 1.0470x over previous
//
#include <hip/hip_runtime.h>

typedef __bf16 bf16x8 __attribute__((ext_vector_type(8)));
typedef float f32x4 __attribute__((ext_vector_type(4)));

__device__ __forceinline__ unsigned short f2bf(float f) {
  union { float f; unsigned u; } v; v.f = f;
  unsigned u = v.u;
  return (unsigned short)((u + 0x7fffu + ((u >> 16) & 1u)) >> 16);  // RNE
}
__device__ __forceinline__ unsigned short f2bf_fast(float f) {
  union { float f; unsigned u; } v; v.f = f;
  return (unsigned short)((v.u + 0x8000u) >> 16);  // round-half-up, for P only
}
__device__ __forceinline__ void gload_lds16(const void* g, void* l) {
  __builtin_amdgcn_global_load_lds(
      (const __attribute__((address_space(1))) unsigned int*)g,
      (__attribute__((address_space(3))) unsigned int*)l, 16, 0, 0);
}
__device__ __forceinline__ void cvt4(const float* __restrict__ s,
                                     unsigned short* __restrict__ d, int u) {
  f32x4 v = ((const f32x4*)s)[u];
  union { unsigned short s[4]; unsigned long long u; } o;
  o.s[0] = f2bf(v[0]); o.s[1] = f2bf(v[1]); o.s[2] = f2bf(v[2]); o.s[3] = f2bf(v[3]);
  ((unsigned long long*)d)[u] = o.u;
}

// LDS tile layout (all 64-elem-row bf16 tiles): row r, 16B-chunk c stored at
// byte r*128 + (c ^ (r&7))*16. Staging: lane stages row (base + ln>>3), slot
// ln&7, so it fetches global chunk (ln&7)^(ln>>3). Reads XOR chunk with lq&7.
// => all 32 banks used per wave b128 read (8-phase minimum, no conflicts).

// ---------------- prep: all f32->bf16 conversions + zero-init, one launch ----
// unit budget: x 1048576 | W1 262144 | Wv 262144 | Wp 262144 | zeroA 1048576
//            | zeroB 16384 | w2t 32768  => total 2932736 units, 11456 blocks
__global__ void prep(const float* __restrict__ x, const float* __restrict__ W1,
                     const float* __restrict__ Wv, const float* __restrict__ Wp,
                     const float* __restrict__ w2, unsigned short* __restrict__ xb,
                     unsigned short* __restrict__ W1b, unsigned short* __restrict__ Wvb,
                     unsigned short* __restrict__ Wpb, unsigned short* __restrict__ w2t,
                     float* __restrict__ zeroA, float* __restrict__ zeroB) {
  int u = blockIdx.x * 256 + threadIdx.x;
  const f32x4 zf = {0.f, 0.f, 0.f, 0.f};
  if (u < 1048576) { cvt4(x, xb, u); return; }       // x: 2*2048*1024 f32
  u -= 1048576;
  if (u < 262144) { cvt4(W1, W1b, u); return; }
  u -= 262144;
  if (u < 262144) { cvt4(Wv, Wvb, u); return; }
  u -= 262144;
  if (u < 262144) { cvt4(Wp, Wpb, u); return; }
  u -= 262144;
  if (u < 1048576) { ((f32x4*)zeroA)[u] = zf; return; }
  u -= 1048576;
  if (u < 16384) { ((f32x4*)zeroB)[u] = zf; return; }
  u -= 16384;
  // w2 (64,2048) f32 -> w2t (2048,64) bf16
  int j = u >> 4, d4 = (u & 15) * 4;
  union { unsigned short s[4]; unsigned long long x; } o;
#pragma unroll
  for (int i = 0; i < 4; ++i) o.s[i] = f2bf(w2[(d4 + i) * 2048 + j]);
  ((unsigned long long*)w2t)[u] = o.x;
}

// ---------------- merged r & vt GEMM (512 blocks, swizzled LDS) -------------
// id<256:  rb = relu(xb @ W1b^T + b1)   M=4096 N=1024
// id>=256: vt = Wvb @ xb^T + bv[row]    M=1024 N=4096
__global__ __launch_bounds__(256) void gemm_rv(
    const unsigned short* __restrict__ xb, const unsigned short* __restrict__ W1b,
    const unsigned short* __restrict__ Wvb, const float* __restrict__ b1,
    const float* __restrict__ bv, unsigned short* __restrict__ rb,
    unsigned short* __restrict__ vtb) {
  __shared__ unsigned short As[128 * 64];
  __shared__ unsigned short Bs[128 * 64];
  int id = blockIdx.x;
  const unsigned short *A, *Bt;
  const float* bias;
  unsigned short* C;
  int N, tileM, tileN, epi;
  if (id < 256) {
    A = xb; Bt = W1b; bias = b1; C = rb; N = 1024; epi = 0;
    tileN = (id & 7) * 128; tileM = (id >> 3) * 128;
  } else {
    id -= 256;
    A = Wvb; Bt = xb; bias = bv; C = vtb; N = 4096; epi = 1;
    tileN = (id & 31) * 128; tileM = (id >> 5) * 128;
  }
  const int tid = threadIdx.x;
  const int wv = tid >> 6, ln = tid & 63;
  const int quad = ln >> 4, lq = ln & 15;
  const int wr = wv >> 1, wc = wv & 1;
  const int rowL = ln >> 3;
  const int kc = (((ln & 7) ^ rowL) & 7) * 8;   // swizzled source chunk
  const int sx = lq & 7;                        // read-side XOR

  f32x4 acc[4][4];
  const f32x4 zf = {0.f, 0.f, 0.f, 0.f};
#pragma unroll
  for (int i = 0; i < 4; ++i)
#pragma unroll
    for (int j = 0; j < 4; ++j) acc[i][j] = zf;

  for (int k0 = 0; k0 < 1024; k0 += 64) {
    __syncthreads();
#pragma unroll
    for (int l = 0; l < 4; ++l) {
      int row = l * 32 + wv * 8 + rowL;
      gload_lds16(A + (tileM + row) * 1024 + k0 + kc, &As[l * 2048 + wv * 512]);
      gload_lds16(Bt + (tileN + row) * 1024 + k0 + kc, &Bs[l * 2048 + wv * 512]);
    }
    __syncthreads();
#pragma unroll
    for (int kk = 0; kk < 2; ++kk) {
      bf16x8 af[4], bfr[4];
#pragma unroll
      for (int mi = 0; mi < 4; ++mi)
        af[mi] = *(const bf16x8*)&As[(wr * 64 + mi * 16 + lq) * 64 + (((kk * 4 + quad) ^ sx) * 8)];
#pragma unroll
      for (int ni = 0; ni < 4; ++ni)
        bfr[ni] = *(const bf16x8*)&Bs[(wc * 64 + ni * 16 + lq) * 64 + (((kk * 4 + quad) ^ sx) * 8)];
#pragma unroll
      for (int mi = 0; mi < 4; ++mi)
#pragma unroll
        for (int ni = 0; ni < 4; ++ni)
          acc[mi][ni] = __builtin_amdgcn_mfma_f32_16x16x32_bf16(af[mi], bfr[ni], acc[mi][ni], 0, 0, 0);
    }
  }
#pragma unroll
  for (int mi = 0; mi < 4; ++mi)
#pragma unroll
    for (int ni = 0; ni < 4; ++ni) {
      int col = tileN + wc * 64 + ni * 16 + lq;
#pragma unroll
      for (int rg = 0; rg < 4; ++rg) {
        int row = tileM + wr * 64 + mi * 16 + quad * 4 + rg;
        float v = acc[mi][ni][rg];
        if (epi == 0) {
          v += bias[col];
          v = v > 0.f ? v : 0.f;
        } else {
          v += bias[row];
        }
        C[row * N + col] = f2bf(v);
      }
    }
}

// ---------------- final GEMM: d_out = yb @ Wp^T + bp (f32 out) --------------
// 128M x 64N tiles -> 512 blocks (2/CU). Wave wv: rows wv*32..wv*32+31.
__global__ __launch_bounds__(256) void gemm_p(
    const unsigned short* __restrict__ A, const unsigned short* __restrict__ Bt,
    const float* __restrict__ bias, float* __restrict__ C) {
  __shared__ unsigned short As[128 * 64];
  __shared__ unsigned short Bs[64 * 64];
  const int tid = threadIdx.x;
  const int wv = tid >> 6, ln = tid & 63;
  const int quad = ln >> 4, lq = ln & 15;
  const int tileM = blockIdx.y * 128, tileN = blockIdx.x * 64;
  const int rowL = ln >> 3;
  const int kc = (((ln & 7) ^ rowL) & 7) * 8;
  const int sx = lq & 7;

  f32x4 acc[2][4];
  const f32x4 zf = {0.f, 0.f, 0.f, 0.f};
#pragma unroll
  for (int i = 0; i < 2; ++i)
#pragma unroll
    for (int j = 0; j < 4; ++j) acc[i][j] = zf;

  for (int k0 = 0; k0 < 1024; k0 += 64) {
    __syncthreads();
#pragma unroll
    for (int l = 0; l < 4; ++l) {
      int row = l * 32 + wv * 8 + rowL;
      gload_lds16(A + (tileM + row) * 1024 + k0 + kc, &As[l * 2048 + wv * 512]);
    }
#pragma unroll
    for (int l = 0; l < 2; ++l) {
      int row = l * 32 + wv * 8 + rowL;
      gload_lds16(Bt + (tileN + row) * 1024 + k0 + kc, &Bs[l * 2048 + wv * 512]);
    }
    __syncthreads();
#pragma unroll
    for (int kk = 0; kk < 2; ++kk) {
      bf16x8 af[2], bfr[4];
#pragma unroll
      for (int mi = 0; mi < 2; ++mi)
        af[mi] = *(const bf16x8*)&As[(wv * 32 + mi * 16 + lq) * 64 + (((kk * 4 + quad) ^ sx) * 8)];
#pragma unroll
      for (int ni = 0; ni < 4; ++ni)
        bfr[ni] = *(const bf16x8*)&Bs[(ni * 16 + lq) * 64 + (((kk * 4 + quad) ^ sx) * 8)];
#pragma unroll
      for (int mi = 0; mi < 2; ++mi)
#pragma unroll
        for (int ni = 0; ni < 4; ++ni)
          acc[mi][ni] = __builtin_amdgcn_mfma_f32_16x16x32_bf16(af[mi], bfr[ni], acc[mi][ni], 0, 0, 0);
    }
  }
#pragma unroll
  for (int mi = 0; mi < 2; ++mi)
#pragma unroll
    for (int ni = 0; ni < 4; ++ni) {
      int col = tileN + ni * 16 + lq;
#pragma unroll
      for (int rg = 0; rg < 4; ++rg) {
        int row = tileM + wv * 32 + mi * 16 + quad * 4 + rg;
        C[row * 1024 + col] = acc[mi][ni][rg] + bias[col];
      }
    }
}

// ---------------- fused synthesizer attention (balanced + split-j) ----------
// Pair t-tiles (p, 31-p): uniform 33 tile-units; split j-range in half ->
// 1024 uniform blocks. Partial sums atomically added into y32 (=d_out scratch)
// and Lsum; normalize pass divides. LDS = 40960B -> 4 blocks/CU.
__global__ __launch_bounds__(256, 4) void attn(
    const unsigned short* __restrict__ r, const unsigned short* __restrict__ w2t,
    const unsigned short* __restrict__ vt, const float* __restrict__ b2,
    float* __restrict__ y32, float* __restrict__ Lsum) {
  __shared__ unsigned short W2s[2][64 * 64];
  __shared__ unsigned short Vs[2][64 * 64];
  __shared__ unsigned short Ps[4][16 * 64];

  const int tid = threadIdx.x;
  const int wv = tid >> 6, ln = tid & 63;
  const int quad = ln >> 4, lq = ln & 15;
  const int pr = blockIdx.x >> 1, half = blockIdx.x & 1;
  const int bh = blockIdx.y, b = bh >> 4, h = bh & 15;
  const int ta = pr, tb = 31 - pr;
  const int sp = (ta >= 8) ? 8 : 16 - ta;          // balanced split point
  const int jlo = half ? sp : 0, jhi = half ? tb : sp - 1;
  const int rowL = ln >> 3;
  const int kc = (((ln & 7) ^ rowL) & 7) * 8;      // swizzled staging chunk
  const int sx = lq & 7;                           // read-side XOR
  const int t0a = ta * 64, t0b = tb * 64;

  // R A-fragments for both t-tiles, straight from global (L2/L3-hot)
  bf16x8 ra[2][2];
  {
    const unsigned short* base = r + (b * 2048 + wv * 16 + lq) * 1024 + h * 64 + quad * 8;
    ra[0][0] = *(const bf16x8*)(base + t0a * 1024);
    ra[0][1] = *(const bf16x8*)(base + t0a * 1024 + 32);
    ra[1][0] = *(const bf16x8*)(base + t0b * 1024);
    ra[1][1] = *(const bf16x8*)(base + t0b * 1024 + 32);
  }

  f32x4 accY[2][4];
  f32x4 accL[2];
  const f32x4 zf = {0.f, 0.f, 0.f, 0.f};
#pragma unroll
  for (int s = 0; s < 2; ++s) {
    accL[s] = zf;
#pragma unroll
    for (int nd = 0; nd < 4; ++nd) accY[s][nd] = zf;
  }
  bf16x8 vones;
#pragma unroll
  for (int i = 0; i < 8; ++i) vones[i] = (__bf16)1.0f;

  auto stage = [&](int jt, int bi) {
    int j0 = jt * 64;
#pragma unroll
    for (int l = 0; l < 2; ++l) {
      int row = l * 32 + wv * 8 + rowL;
      gload_lds16(w2t + (j0 + row) * 64 + kc, &W2s[bi][l * 2048 + wv * 512]);
      gload_lds16(vt + (h * 64 + row) * 4096 + b * 2048 + j0 + kc,
                  &Vs[bi][l * 2048 + wv * 512]);
    }
  };

  stage(jlo, 0);
  for (int jt = jlo; jt <= jhi; ++jt) {
    const int cb = (jt - jlo) & 1;
    __syncthreads();                 // staging(jt) landed; prev readers of other buf done
    if (jt < jhi) stage(jt + 1, cb ^ 1);  // prefetch overlaps compute below
    const int j0 = jt * 64;

#define TILE(S, T0, TT)                                                         \
    {                                                                           \
      f32x4 sv[4] = {zf, zf, zf, zf};                                           \
      _Pragma("unroll") for (int kk = 0; kk < 2; ++kk) {                        \
        _Pragma("unroll") for (int ni = 0; ni < 4; ++ni) {                      \
          bf16x8 bb = *(const bf16x8*)&W2s[cb][(ni * 16 + lq) * 64 + (((kk * 4 + quad) ^ sx) * 8)]; \
          sv[ni] = __builtin_amdgcn_mfma_f32_16x16x32_bf16(ra[S][kk], bb, sv[ni], 0, 0, 0); \
        }                                                                       \
      }                                                                         \
      const bool diag = (jt == (TT));                                           \
      _Pragma("unroll") for (int ni = 0; ni < 4; ++ni) {                        \
        int j = j0 + ni * 16 + lq;                                              \
        float bj = b2[j];                                                       \
        _Pragma("unroll") for (int rg = 0; rg < 4; ++rg) {                      \
          float p = __expf(sv[ni][rg] + bj);                                    \
          if (diag) {                                                           \
            int t = (T0) + wv * 16 + quad * 4 + rg;                             \
            p = (j <= t) ? p : 0.f;                                             \
          }                                                                     \
          Ps[wv][(quad * 4 + rg) * 64 +                                         \
                 (((ni * 2 + (lq >> 3)) ^ ((quad * 4 + rg) & 7)) * 8) + (lq & 7)] = f2bf_fast(p); \
        }                                                                       \
      }                                                                         \
      _Pragma("unroll") for (int kk = 0; kk < 2; ++kk) {                        \
        bf16x8 pa = *(const bf16x8*)&Ps[wv][lq * 64 + (((kk * 4 + quad) ^ sx) * 8)]; \
        _Pragma("unroll") for (int nd = 0; nd < 4; ++nd) {                      \
          bf16x8 bb = *(const bf16x8*)&Vs[cb][(nd * 16 + lq) * 64 + (((kk * 4 + quad) ^ sx) * 8)]; \
          accY[S][nd] = __builtin_amdgcn_mfma_f32_16x16x32_bf16(pa, bb, accY[S][nd], 0, 0, 0); \
        }                                                                       \
        accL[S] = __builtin_amdgcn_mfma_f32_16x16x32_bf16(pa, vones, accL[S], 0, 0, 0); \
      }                                                                         \
    }

    if (jt <= ta) TILE(0, t0a, ta);
    TILE(1, t0b, tb);
#undef TILE
  }

#pragma unroll
  for (int s = 0; s < 2; ++s) {
    if (!(s == 0 && jlo > ta)) {
      const int t0s = s ? t0b : t0a;
#pragma unroll
      for (int nd = 0; nd < 4; ++nd)
#pragma unroll
        for (int rg = 0; rg < 4; ++rg) {
          int t = t0s + wv * 16 + quad * 4 + rg;
          atomicAdd(&y32[(b * 2048 + t) * 1024 + h * 64 + nd * 16 + lq], accY[s][nd][rg]);
        }
      if (lq == 0) {
#pragma unroll
        for (int rg = 0; rg < 4; ++rg) {
          int t = t0s + wv * 16 + quad * 4 + rg;
          atomicAdd(&Lsum[(b * 2048 + t) * 16 + h], accL[s][rg]);
        }
      }
    }
  }
}

// ---------------- normalize: yb = bf16(y32 / Lsum) --------------------------
__global__ void normfin(const float* __restrict__ y32, const float* __restrict__ Lsum,
                        unsigned short* __restrict__ yb) {
  int u = blockIdx.x * 256 + threadIdx.x;   // 1048576 units of f32x4
  int tg = u >> 8, h = (u & 255) >> 4;      // c = (u&255)*4; h = c>>6 = (u&255)>>4
  float inv = 1.0f / Lsum[tg * 16 + h];
  f32x4 v = ((const f32x4*)y32)[u];
  union { unsigned short s[4]; unsigned long long x; } o;
  o.s[0] = f2bf(v[0] * inv); o.s[1] = f2bf(v[1] * inv);
  o.s[2] = f2bf(v[2] * inv); o.s[3] = f2bf(v[3] * inv);
  ((unsigned long long*)yb)[u] = o.x;
}

// ---------------- launch ----------------
extern "C" void kernel_launch(void* const* d_in, const int* in_sizes, int n_in,
                              void* d_out, int out_size, void* d_ws, size_t ws_size,
                              hipStream_t stream) {
  const float* x  = (const float*)d_in[0];
  const float* W1 = (const float*)d_in[1];
  const float* b1 = (const float*)d_in[2];
  const float* w2 = (const float*)d_in[3];
  const float* b2 = (const float*)d_in[4];
  const float* Wv = (const float*)d_in[5];
  const float* bv = (const float*)d_in[6];
  const float* Wp = (const float*)d_in[7];
  const float* bp = (const float*)d_in[8];

  unsigned short* ws  = (unsigned short*)d_ws;
  unsigned short* xb  = ws;                 // 4096x1024 bf16
  unsigned short* W1b = ws + 4194304;       // 1024x1024
  unsigned short* Wvb = ws + 5242880;       // 1024x1024
  unsigned short* Wpb = ws + 6291456;       // 1024x1024
  unsigned short* w2t = ws + 7340032;       // 2048x64
  unsigned short* rb  = ws + 7471104;       // 4096x1024
  unsigned short* vt  = ws + 11665408;      // 1024x4096
  unsigned short* yb  = ws + 15859712;      // 4096x1024
  float* Lsum = (float*)(ws + 20054016);    // 4096x16 f32
  float* y32  = (float*)d_out;              // 16MB f32 scratch, overwritten by gemm_p

  prep<<<11456, 256, 0, stream>>>(x, W1, Wv, Wp, w2, xb, W1b, Wvb, Wpb, w2t, y32, Lsum);
  gemm_rv<<<512, 256, 0, stream>>>(xb, W1b, Wvb, b1, bv, rb, vt);
  attn<<<dim3(32, 32), 256, 0, stream>>>(rb, w2t, vt, b2, y32, Lsum);
  normfin<<<4096, 256, 0, stream>>>(y32, Lsum, yb);
  gemm_p<<<dim3(16, 32), 256, 0, stream>>>(yb, Wpb, bp, (float*)d_out);
}

// Round 5
// 214.179 us; speedup vs baseline: 1.2788x; 1.0002x over previous
//
#include <hip/hip_runtime.h>

typedef __bf16 bf16x8 __attribute__((ext_vector_type(8)));
typedef float f32x4 __attribute__((ext_vector_type(4)));

__device__ __forceinline__ unsigned short f2bf(float f) {
  union { float f; unsigned u; } v; v.f = f;
  unsigned u = v.u;
  return (unsigned short)((u + 0x7fffu + ((u >> 16) & 1u)) >> 16);  // RNE
}
__device__ __forceinline__ unsigned short f2bf_fast(float f) {
  union { float f; unsigned u; } v; v.f = f;
  return (unsigned short)((v.u + 0x8000u) >> 16);  // round-half-up, for P only
}
__device__ __forceinline__ void gload_lds16(const void* g, void* l) {
  __builtin_amdgcn_global_load_lds(
      (const __attribute__((address_space(1))) unsigned int*)g,
      (__attribute__((address_space(3))) unsigned int*)l, 16, 0, 0);
}
__device__ __forceinline__ void cvt4(const float* __restrict__ s,
                                     unsigned short* __restrict__ d, int u) {
  f32x4 v = ((const f32x4*)s)[u];
  union { unsigned short s[4]; unsigned long long u; } o;
  o.s[0] = f2bf(v[0]); o.s[1] = f2bf(v[1]); o.s[2] = f2bf(v[2]); o.s[3] = f2bf(v[3]);
  ((unsigned long long*)d)[u] = o.u;
}

// LDS tile layout (64-elem-row bf16 tiles): row r, 16B-chunk c stored at byte
// r*128 + (c ^ (r&7))*16. Staging lane fetches global chunk (ln&7)^(ln>>3).
// Reads XOR chunk with lq&7 -> all 32 banks per wave b128 read.

// ---------------- prep: f32->bf16 conversions + Lsb zero, one launch --------
// units: x 1048576 | W1 262144 | Wv 262144 | Wp 262144 | Lsb 16384 | w2t 32768
// total 1884160 -> 7360 blocks
__global__ void prep(const float* __restrict__ x, const float* __restrict__ W1,
                     const float* __restrict__ Wv, const float* __restrict__ Wp,
                     const float* __restrict__ w2, unsigned short* __restrict__ xb,
                     unsigned short* __restrict__ W1b, unsigned short* __restrict__ Wvb,
                     unsigned short* __restrict__ Wpb, unsigned short* __restrict__ w2t,
                     float* __restrict__ Lsb) {
  int u = blockIdx.x * 256 + threadIdx.x;
  const f32x4 zf = {0.f, 0.f, 0.f, 0.f};
  if (u < 1048576) { cvt4(x, xb, u); return; }
  u -= 1048576;
  if (u < 262144) { cvt4(W1, W1b, u); return; }
  u -= 262144;
  if (u < 262144) { cvt4(Wv, Wvb, u); return; }
  u -= 262144;
  if (u < 262144) { cvt4(Wp, Wpb, u); return; }
  u -= 262144;
  if (u < 16384) { ((f32x4*)Lsb)[u] = zf; return; }
  u -= 16384;
  // w2 (64,2048) f32 -> w2t (2048,64) bf16
  int j = u >> 4, d4 = (u & 15) * 4;
  union { unsigned short s[4]; unsigned long long x; } o;
#pragma unroll
  for (int i = 0; i < 4; ++i) o.s[i] = f2bf(w2[(d4 + i) * 2048 + j]);
  ((unsigned long long*)w2t)[u] = o.x;
}

// ---------------- merged r & vt GEMM (512 blocks, swizzled LDS) -------------
__global__ __launch_bounds__(256) void gemm_rv(
    const unsigned short* __restrict__ xb, const unsigned short* __restrict__ W1b,
    const unsigned short* __restrict__ Wvb, const float* __restrict__ b1,
    const float* __restrict__ bv, unsigned short* __restrict__ rb,
    unsigned short* __restrict__ vtb) {
  __shared__ unsigned short As[128 * 64];
  __shared__ unsigned short Bs[128 * 64];
  int id = blockIdx.x;
  const unsigned short *A, *Bt;
  const float* bias;
  unsigned short* C;
  int N, tileM, tileN, epi;
  if (id < 256) {
    A = xb; Bt = W1b; bias = b1; C = rb; N = 1024; epi = 0;
    tileN = (id & 7) * 128; tileM = (id >> 3) * 128;
  } else {
    id -= 256;
    A = Wvb; Bt = xb; bias = bv; C = vtb; N = 4096; epi = 1;
    tileN = (id & 31) * 128; tileM = (id >> 5) * 128;
  }
  const int tid = threadIdx.x;
  const int wv = tid >> 6, ln = tid & 63;
  const int quad = ln >> 4, lq = ln & 15;
  const int wr = wv >> 1, wc = wv & 1;
  const int rowL = ln >> 3;
  const int kc = (((ln & 7) ^ rowL) & 7) * 8;
  const int sx = lq & 7;
  const int ko0 = (quad ^ sx) * 8, ko1 = ((4 + quad) ^ sx) * 8;

  f32x4 acc[4][4];
  const f32x4 zf = {0.f, 0.f, 0.f, 0.f};
#pragma unroll
  for (int i = 0; i < 4; ++i)
#pragma unroll
    for (int j = 0; j < 4; ++j) acc[i][j] = zf;

  for (int k0 = 0; k0 < 1024; k0 += 64) {
    __syncthreads();
#pragma unroll
    for (int l = 0; l < 4; ++l) {
      int row = l * 32 + wv * 8 + rowL;
      gload_lds16(A + (tileM + row) * 1024 + k0 + kc, &As[l * 2048 + wv * 512]);
      gload_lds16(Bt + (tileN + row) * 1024 + k0 + kc, &Bs[l * 2048 + wv * 512]);
    }
    __syncthreads();
#pragma unroll
    for (int kk = 0; kk < 2; ++kk) {
      const int ko = kk ? ko1 : ko0;
      bf16x8 af[4], bfr[4];
#pragma unroll
      for (int mi = 0; mi < 4; ++mi)
        af[mi] = *(const bf16x8*)&As[(wr * 64 + mi * 16 + lq) * 64 + ko];
#pragma unroll
      for (int ni = 0; ni < 4; ++ni)
        bfr[ni] = *(const bf16x8*)&Bs[(wc * 64 + ni * 16 + lq) * 64 + ko];
#pragma unroll
      for (int mi = 0; mi < 4; ++mi)
#pragma unroll
        for (int ni = 0; ni < 4; ++ni)
          acc[mi][ni] = __builtin_amdgcn_mfma_f32_16x16x32_bf16(af[mi], bfr[ni], acc[mi][ni], 0, 0, 0);
    }
  }
#pragma unroll
  for (int mi = 0; mi < 4; ++mi)
#pragma unroll
    for (int ni = 0; ni < 4; ++ni) {
      int col = tileN + wc * 64 + ni * 16 + lq;
#pragma unroll
      for (int rg = 0; rg < 4; ++rg) {
        int row = tileM + wr * 64 + mi * 16 + quad * 4 + rg;
        float v = acc[mi][ni][rg];
        if (epi == 0) {
          v += bias[col];
          v = v > 0.f ? v : 0.f;
        } else {
          v += bias[row];
        }
        C[row * N + col] = f2bf(v);
      }
    }
}

// ---------------- final GEMM: d_out = yb @ Wp^T + bp (f32 out) --------------
// 128M x 64N tiles -> 512 blocks (2/CU).
__global__ __launch_bounds__(256) void gemm_p(
    const unsigned short* __restrict__ A, const unsigned short* __restrict__ Bt,
    const float* __restrict__ bias, float* __restrict__ C) {
  __shared__ unsigned short As[128 * 64];
  __shared__ unsigned short Bs[64 * 64];
  const int tid = threadIdx.x;
  const int wv = tid >> 6, ln = tid & 63;
  const int quad = ln >> 4, lq = ln & 15;
  const int tileM = blockIdx.y * 128, tileN = blockIdx.x * 64;
  const int rowL = ln >> 3;
  const int kc = (((ln & 7) ^ rowL) & 7) * 8;
  const int sx = lq & 7;
  const int ko0 = (quad ^ sx) * 8, ko1 = ((4 + quad) ^ sx) * 8;

  f32x4 acc[2][4];
  const f32x4 zf = {0.f, 0.f, 0.f, 0.f};
#pragma unroll
  for (int i = 0; i < 2; ++i)
#pragma unroll
    for (int j = 0; j < 4; ++j) acc[i][j] = zf;

  for (int k0 = 0; k0 < 1024; k0 += 64) {
    __syncthreads();
#pragma unroll
    for (int l = 0; l < 4; ++l) {
      int row = l * 32 + wv * 8 + rowL;
      gload_lds16(A + (tileM + row) * 1024 + k0 + kc, &As[l * 2048 + wv * 512]);
    }
#pragma unroll
    for (int l = 0; l < 2; ++l) {
      int row = l * 32 + wv * 8 + rowL;
      gload_lds16(Bt + (tileN + row) * 1024 + k0 + kc, &Bs[l * 2048 + wv * 512]);
    }
    __syncthreads();
#pragma unroll
    for (int kk = 0; kk < 2; ++kk) {
      const int ko = kk ? ko1 : ko0;
      bf16x8 af[2], bfr[4];
#pragma unroll
      for (int mi = 0; mi < 2; ++mi)
        af[mi] = *(const bf16x8*)&As[(wv * 32 + mi * 16 + lq) * 64 + ko];
#pragma unroll
      for (int ni = 0; ni < 4; ++ni)
        bfr[ni] = *(const bf16x8*)&Bs[(ni * 16 + lq) * 64 + ko];
#pragma unroll
      for (int mi = 0; mi < 2; ++mi)
#pragma unroll
        for (int ni = 0; ni < 4; ++ni)
          acc[mi][ni] = __builtin_amdgcn_mfma_f32_16x16x32_bf16(af[mi], bfr[ni], acc[mi][ni], 0, 0, 0);
    }
  }
#pragma unroll
  for (int mi = 0; mi < 2; ++mi)
#pragma unroll
    for (int ni = 0; ni < 4; ++ni) {
      int col = tileN + ni * 16 + lq;
#pragma unroll
      for (int rg = 0; rg < 4; ++rg) {
        int row = tileM + wv * 32 + mi * 16 + quad * 4 + rg;
        C[row * 1024 + col] = acc[mi][ni][rg] + bias[col];
      }
    }
}

// ---------------- fused synthesizer attention (no atomics) ------------------
// Pair t-tiles (p, 31-p); split j in half -> 1024 uniform blocks. half0 ->
// (ya, Lsa) plain stores (covers every row exactly once); half1 -> (yb_, Lsb)
// (tile-a rows untouched when pr<8 -> Lsb stays 0, normfin selects).
__global__ __launch_bounds__(256, 4) void attn(
    const unsigned short* __restrict__ r, const unsigned short* __restrict__ w2t,
    const unsigned short* __restrict__ vt, const float* __restrict__ b2,
    float* __restrict__ ya, float* __restrict__ yb_,
    float* __restrict__ Lsa, float* __restrict__ Lsb) {
  __shared__ unsigned short W2s[2][64 * 64];
  __shared__ unsigned short Vs[2][64 * 64];
  __shared__ unsigned short Ps[4][16 * 64];

  const int tid = threadIdx.x;
  const int wv = tid >> 6, ln = tid & 63;
  const int quad = ln >> 4, lq = ln & 15;
  const int pr = blockIdx.x >> 1, half = blockIdx.x & 1;
  const int bh = blockIdx.y, b = bh >> 4, h = bh & 15;
  const int ta = pr, tb = 31 - pr;
  const int sp = (ta >= 8) ? 8 : 16 - ta;
  const int jlo = half ? sp : 0, jhi = half ? tb : sp - 1;
  const int rowL = ln >> 3;
  const int kc = (((ln & 7) ^ rowL) & 7) * 8;
  const int sx = lq & 7;
  const int ko0 = (quad ^ sx) * 8, ko1 = ((4 + quad) ^ sx) * 8;
  const int t0a = ta * 64, t0b = tb * 64;
  float* yo = half ? yb_ : ya;
  float* Lo = half ? Lsb : Lsa;

  bf16x8 ra[2][2];
  {
    const unsigned short* base = r + (b * 2048 + wv * 16 + lq) * 1024 + h * 64 + quad * 8;
    ra[0][0] = *(const bf16x8*)(base + t0a * 1024);
    ra[0][1] = *(const bf16x8*)(base + t0a * 1024 + 32);
    ra[1][0] = *(const bf16x8*)(base + t0b * 1024);
    ra[1][1] = *(const bf16x8*)(base + t0b * 1024 + 32);
  }

  f32x4 accY[2][4];
  f32x4 accL[2];
  const f32x4 zf = {0.f, 0.f, 0.f, 0.f};
#pragma unroll
  for (int s = 0; s < 2; ++s) {
    accL[s] = zf;
#pragma unroll
    for (int nd = 0; nd < 4; ++nd) accY[s][nd] = zf;
  }
  bf16x8 vones;
#pragma unroll
  for (int i = 0; i < 8; ++i) vones[i] = (__bf16)1.0f;

  auto stage = [&](int jt, int bi) {
    int j0 = jt * 64;
#pragma unroll
    for (int l = 0; l < 2; ++l) {
      int row = l * 32 + wv * 8 + rowL;
      gload_lds16(w2t + (j0 + row) * 64 + kc, &W2s[bi][l * 2048 + wv * 512]);
      gload_lds16(vt + (h * 64 + row) * 4096 + b * 2048 + j0 + kc,
                  &Vs[bi][l * 2048 + wv * 512]);
    }
  };

  stage(jlo, 0);
  for (int jt = jlo; jt <= jhi; ++jt) {
    const int cb = (jt - jlo) & 1;
    __syncthreads();
    if (jt < jhi) stage(jt + 1, cb ^ 1);
    const int j0 = jt * 64;

    // hoisted per-iter loads: b2 tile + W2 B-fragments (shared by both TILEs)
    float bj[4];
#pragma unroll
    for (int ni = 0; ni < 4; ++ni) bj[ni] = b2[j0 + ni * 16 + lq];
    bf16x8 w2f[2][4];
#pragma unroll
    for (int ni = 0; ni < 4; ++ni) {
      w2f[0][ni] = *(const bf16x8*)&W2s[cb][(ni * 16 + lq) * 64 + ko0];
      w2f[1][ni] = *(const bf16x8*)&W2s[cb][(ni * 16 + lq) * 64 + ko1];
    }

#define TILE(S, T0, TT)                                                         \
    {                                                                           \
      f32x4 sv[4] = {zf, zf, zf, zf};                                           \
      _Pragma("unroll") for (int kk = 0; kk < 2; ++kk) {                        \
        _Pragma("unroll") for (int ni = 0; ni < 4; ++ni)                        \
          sv[ni] = __builtin_amdgcn_mfma_f32_16x16x32_bf16(ra[S][kk], w2f[kk][ni], sv[ni], 0, 0, 0); \
      }                                                                         \
      const bool diag = (jt == (TT));                                           \
      _Pragma("unroll") for (int ni = 0; ni < 4; ++ni) {                        \
        int j = j0 + ni * 16 + lq;                                              \
        _Pragma("unroll") for (int rg = 0; rg < 4; ++rg) {                      \
          float p = __expf(sv[ni][rg] + bj[ni]);                                \
          if (diag) {                                                           \
            int t = (T0) + wv * 16 + quad * 4 + rg;                             \
            p = (j <= t) ? p : 0.f;                                             \
          }                                                                     \
          Ps[wv][(quad * 4 + rg) * 64 +                                         \
                 (((ni * 2 + (lq >> 3)) ^ ((quad * 4 + rg) & 7)) * 8) + (lq & 7)] = f2bf_fast(p); \
        }                                                                       \
      }                                                                         \
      _Pragma("unroll") for (int kk = 0; kk < 2; ++kk) {                        \
        const int ko = kk ? ko1 : ko0;                                          \
        bf16x8 pa = *(const bf16x8*)&Ps[wv][lq * 64 + ko];                      \
        _Pragma("unroll") for (int nd = 0; nd < 4; ++nd) {                      \
          bf16x8 bb = *(const bf16x8*)&Vs[cb][(nd * 16 + lq) * 64 + ko];        \
          accY[S][nd] = __builtin_amdgcn_mfma_f32_16x16x32_bf16(pa, bb, accY[S][nd], 0, 0, 0); \
        }                                                                       \
        accL[S] = __builtin_amdgcn_mfma_f32_16x16x32_bf16(pa, vones, accL[S], 0, 0, 0); \
      }                                                                         \
    }

    if (jt <= ta) TILE(0, t0a, ta);
    TILE(1, t0b, tb);
#undef TILE
  }

#pragma unroll
  for (int s = 0; s < 2; ++s) {
    if (s == 0 && jlo > ta) continue;
    const int t0s = s ? t0b : t0a;
#pragma unroll
    for (int nd = 0; nd < 4; ++nd)
#pragma unroll
      for (int rg = 0; rg < 4; ++rg) {
        int t = t0s + wv * 16 + quad * 4 + rg;
        yo[(b * 2048 + t) * 1024 + h * 64 + nd * 16 + lq] = accY[s][nd][rg];
      }
    if (lq == 0) {
#pragma unroll
      for (int rg = 0; rg < 4; ++rg) {
        int t = t0s + wv * 16 + quad * 4 + rg;
        Lo[(b * 2048 + t) * 16 + h] = accL[s][rg];
      }
    }
  }
}

// ---------------- normalize: yb = bf16((ya + sel·yb_) / (La+Lb)) ------------
__global__ void normfin(const float* __restrict__ ya, const float* __restrict__ yb4,
                        const float* __restrict__ Lsa, const float* __restrict__ Lsb,
                        unsigned short* __restrict__ yb) {
  int u = blockIdx.x * 256 + threadIdx.x;   // 1048576 f32x4 units
  int tg = u >> 8, h = (u & 255) >> 4;
  float La = Lsa[tg * 16 + h], Lb = Lsb[tg * 16 + h];
  float inv = 1.0f / (La + Lb);
  f32x4 a = ((const f32x4*)ya)[u];
  f32x4 bq = ((const f32x4*)yb4)[u];
  bool m = (Lb != 0.0f);
  union { unsigned short s[4]; unsigned long long x; } o;
#pragma unroll
  for (int i = 0; i < 4; ++i) {
    float v = (a[i] + (m ? bq[i] : 0.0f)) * inv;
    o.s[i] = f2bf(v);
  }
  ((unsigned long long*)yb)[u] = o.x;
}

// ---------------- launch ----------------
extern "C" void kernel_launch(void* const* d_in, const int* in_sizes, int n_in,
                              void* d_out, int out_size, void* d_ws, size_t ws_size,
                              hipStream_t stream) {
  const float* x  = (const float*)d_in[0];
  const float* W1 = (const float*)d_in[1];
  const float* b1 = (const float*)d_in[2];
  const float* w2 = (const float*)d_in[3];
  const float* b2 = (const float*)d_in[4];
  const float* Wv = (const float*)d_in[5];
  const float* bv = (const float*)d_in[6];
  const float* Wp = (const float*)d_in[7];
  const float* bp = (const float*)d_in[8];

  unsigned short* ws  = (unsigned short*)d_ws;
  unsigned short* xb  = ws;                 // 4096x1024 bf16
  unsigned short* W1b = ws + 4194304;       // 1024x1024
  unsigned short* Wvb = ws + 5242880;       // 1024x1024
  unsigned short* Wpb = ws + 6291456;       // 1024x1024
  unsigned short* w2t = ws + 7340032;       // 2048x64
  unsigned short* rb  = ws + 7471104;       // 4096x1024
  unsigned short* vt  = ws + 11665408;      // 1024x4096
  unsigned short* yb  = ws + 15859712;      // 4096x1024 bf16
  float* y32b = (float*)(ws + 20054016);    // 4096x1024 f32 (16MB)
  float* Lsa  = (float*)(ws + 28442624);    // 4096x16 f32
  float* Lsb  = (float*)(ws + 28573696);    // 4096x16 f32
  float* y32a = (float*)d_out;              // f32 scratch, overwritten by gemm_p

  prep<<<7360, 256, 0, stream>>>(x, W1, Wv, Wp, w2, xb, W1b, Wvb, Wpb, w2t, Lsb);
  gemm_rv<<<512, 256, 0, stream>>>(xb, W1b, Wvb, b1, bv, rb, vt);
  attn<<<dim3(32, 32), 256, 0, stream>>>(rb, w2t, vt, b2, y32a, y32b, Lsa, Lsb);
  normfin<<<4096, 256, 0, stream>>>(y32a, y32b, Lsa, Lsb, yb);
  gemm_p<<<dim3(16, 32), 256, 0, stream>>>(yb, Wpb, bp, (float*)d_out);
}

// Round 6
// 192.470 us; speedup vs baseline: 1.4230x; 1.1128x over previous
//
#include <hip/hip_runtime.h>

typedef __bf16 bf16x8 __attribute__((ext_vector_type(8)));
typedef float f32x4 __attribute__((ext_vector_type(4)));

__device__ __forceinline__ unsigned short f2bf(float f) {
  union { float f; unsigned u; } v; v.f = f;
  unsigned u = v.u;
  return (unsigned short)((u + 0x7fffu + ((u >> 16) & 1u)) >> 16);  // RNE
}
__device__ __forceinline__ unsigned short f2bf_fast(float f) {
  union { float f; unsigned u; } v; v.f = f;
  return (unsigned short)((v.u + 0x8000u) >> 16);  // round-half-up, for P only
}
__device__ __forceinline__ void gload_lds16(const void* g, void* l) {
  __builtin_amdgcn_global_load_lds(
      (const __attribute__((address_space(1))) unsigned int*)g,
      (__attribute__((address_space(3))) unsigned int*)l, 16, 0, 0);
}
__device__ __forceinline__ void cvt4(const float* __restrict__ s,
                                     unsigned short* __restrict__ d, int u) {
  f32x4 v = ((const f32x4*)s)[u];
  union { unsigned short s[4]; unsigned long long u; } o;
  o.s[0] = f2bf(v[0]); o.s[1] = f2bf(v[1]); o.s[2] = f2bf(v[2]); o.s[3] = f2bf(v[3]);
  ((unsigned long long*)d)[u] = o.u;
}

// LDS tile layout (64-elem-row bf16 tiles): row r, 16B-chunk c stored at byte
// r*128 + (c ^ (r&7))*16. Staging lane fetches global chunk (ln&7)^(ln>>3).
// Reads XOR chunk with lq&7 -> all 32 banks per wave b128 read.

// ---------------- prep: f32->bf16 conversions + ebj, one launch -------------
// units: x 1048576 | W1 262144 | Wv 262144 | Wp 262144 | w2t 32768 | ebj 512
// total 1868288 -> 7298 blocks
__global__ void prep(const float* __restrict__ x, const float* __restrict__ W1,
                     const float* __restrict__ Wv, const float* __restrict__ Wp,
                     const float* __restrict__ w2, const float* __restrict__ b2,
                     unsigned short* __restrict__ xb, unsigned short* __restrict__ W1b,
                     unsigned short* __restrict__ Wvb, unsigned short* __restrict__ Wpb,
                     unsigned short* __restrict__ w2t, unsigned short* __restrict__ ebj) {
  int u = blockIdx.x * 256 + threadIdx.x;
  if (u < 1048576) { cvt4(x, xb, u); return; }
  u -= 1048576;
  if (u < 262144) { cvt4(W1, W1b, u); return; }
  u -= 262144;
  if (u < 262144) { cvt4(Wv, Wvb, u); return; }
  u -= 262144;
  if (u < 262144) { cvt4(Wp, Wpb, u); return; }
  u -= 262144;
  if (u < 32768) {
    // w2 (64,2048) f32 -> w2t (2048,64) bf16
    int j = u >> 4, d4 = (u & 15) * 4;
    union { unsigned short s[4]; unsigned long long x; } o;
#pragma unroll
    for (int i = 0; i < 4; ++i) o.s[i] = f2bf(w2[(d4 + i) * 2048 + j]);
    ((unsigned long long*)w2t)[u] = o.x;
    return;
  }
  u -= 32768;
  // ebj = bf16(exp(b2)), 2048 elems in 512 x4-units
  union { unsigned short s[4]; unsigned long long x; } o;
#pragma unroll
  for (int i = 0; i < 4; ++i) o.s[i] = f2bf(__expf(b2[u * 4 + i]));
  ((unsigned long long*)ebj)[u] = o.x;
}

// ---------------- merged r & vt GEMM (512 blocks, swizzled LDS) -------------
// id<256:  rb = relu(xb @ W1b^T + b1)            M=4096 N=1024
// id>=256: vt = (Wvb @ xb^T + bv[row])*exp(b2[col&2047])   M=1024 N=4096
__global__ __launch_bounds__(256) void gemm_rv(
    const unsigned short* __restrict__ xb, const unsigned short* __restrict__ W1b,
    const unsigned short* __restrict__ Wvb, const float* __restrict__ b1,
    const float* __restrict__ bv, const float* __restrict__ b2,
    unsigned short* __restrict__ rb, unsigned short* __restrict__ vtb) {
  __shared__ unsigned short As[128 * 64];
  __shared__ unsigned short Bs[128 * 64];
  int id = blockIdx.x;
  const unsigned short *A, *Bt;
  const float* bias;
  unsigned short* C;
  int N, tileM, tileN, epi;
  if (id < 256) {
    A = xb; Bt = W1b; bias = b1; C = rb; N = 1024; epi = 0;
    tileN = (id & 7) * 128; tileM = (id >> 3) * 128;
  } else {
    id -= 256;
    A = Wvb; Bt = xb; bias = bv; C = vtb; N = 4096; epi = 1;
    tileN = (id & 31) * 128; tileM = (id >> 5) * 128;
  }
  const int tid = threadIdx.x;
  const int wv = tid >> 6, ln = tid & 63;
  const int quad = ln >> 4, lq = ln & 15;
  const int wr = wv >> 1, wc = wv & 1;
  const int rowL = ln >> 3;
  const int kc = (((ln & 7) ^ rowL) & 7) * 8;
  const int sx = lq & 7;
  const int ko0 = (quad ^ sx) * 8, ko1 = ((4 + quad) ^ sx) * 8;

  f32x4 acc[4][4];
  const f32x4 zf = {0.f, 0.f, 0.f, 0.f};
#pragma unroll
  for (int i = 0; i < 4; ++i)
#pragma unroll
    for (int j = 0; j < 4; ++j) acc[i][j] = zf;

  for (int k0 = 0; k0 < 1024; k0 += 64) {
    __syncthreads();
#pragma unroll
    for (int l = 0; l < 4; ++l) {
      int row = l * 32 + wv * 8 + rowL;
      gload_lds16(A + (tileM + row) * 1024 + k0 + kc, &As[l * 2048 + wv * 512]);
      gload_lds16(Bt + (tileN + row) * 1024 + k0 + kc, &Bs[l * 2048 + wv * 512]);
    }
    __syncthreads();
#pragma unroll
    for (int kk = 0; kk < 2; ++kk) {
      const int ko = kk ? ko1 : ko0;
      bf16x8 af[4], bfr[4];
#pragma unroll
      for (int mi = 0; mi < 4; ++mi)
        af[mi] = *(const bf16x8*)&As[(wr * 64 + mi * 16 + lq) * 64 + ko];
#pragma unroll
      for (int ni = 0; ni < 4; ++ni)
        bfr[ni] = *(const bf16x8*)&Bs[(wc * 64 + ni * 16 + lq) * 64 + ko];
#pragma unroll
      for (int mi = 0; mi < 4; ++mi)
#pragma unroll
        for (int ni = 0; ni < 4; ++ni)
          acc[mi][ni] = __builtin_amdgcn_mfma_f32_16x16x32_bf16(af[mi], bfr[ni], acc[mi][ni], 0, 0, 0);
    }
  }
#pragma unroll
  for (int ni = 0; ni < 4; ++ni) {
    int col = tileN + wc * 64 + ni * 16 + lq;
    float eb = (epi == 1) ? __expf(b2[col & 2047]) : 0.0f;
#pragma unroll
    for (int mi = 0; mi < 4; ++mi) {
#pragma unroll
      for (int rg = 0; rg < 4; ++rg) {
        int row = tileM + wr * 64 + mi * 16 + quad * 4 + rg;
        float v = acc[mi][ni][rg];
        if (epi == 0) {
          v += bias[col];
          v = v > 0.f ? v : 0.f;
        } else {
          v = (v + bias[row]) * eb;
        }
        C[row * N + col] = f2bf(v);
      }
    }
  }
}

// ---------------- final GEMM: d_out = yb @ Wp^T + bp (f32 out) --------------
// 128M x 64N tiles -> 512 blocks (2/CU).
__global__ __launch_bounds__(256) void gemm_p(
    const unsigned short* __restrict__ A, const unsigned short* __restrict__ Bt,
    const float* __restrict__ bias, float* __restrict__ C) {
  __shared__ unsigned short As[128 * 64];
  __shared__ unsigned short Bs[64 * 64];
  const int tid = threadIdx.x;
  const int wv = tid >> 6, ln = tid & 63;
  const int quad = ln >> 4, lq = ln & 15;
  const int tileM = blockIdx.y * 128, tileN = blockIdx.x * 64;
  const int rowL = ln >> 3;
  const int kc = (((ln & 7) ^ rowL) & 7) * 8;
  const int sx = lq & 7;
  const int ko0 = (quad ^ sx) * 8, ko1 = ((4 + quad) ^ sx) * 8;

  f32x4 acc[2][4];
  const f32x4 zf = {0.f, 0.f, 0.f, 0.f};
#pragma unroll
  for (int i = 0; i < 2; ++i)
#pragma unroll
    for (int j = 0; j < 4; ++j) acc[i][j] = zf;

  for (int k0 = 0; k0 < 1024; k0 += 64) {
    __syncthreads();
#pragma unroll
    for (int l = 0; l < 4; ++l) {
      int row = l * 32 + wv * 8 + rowL;
      gload_lds16(A + (tileM + row) * 1024 + k0 + kc, &As[l * 2048 + wv * 512]);
    }
#pragma unroll
    for (int l = 0; l < 2; ++l) {
      int row = l * 32 + wv * 8 + rowL;
      gload_lds16(Bt + (tileN + row) * 1024 + k0 + kc, &Bs[l * 2048 + wv * 512]);
    }
    __syncthreads();
#pragma unroll
    for (int kk = 0; kk < 2; ++kk) {
      const int ko = kk ? ko1 : ko0;
      bf16x8 af[2], bfr[4];
#pragma unroll
      for (int mi = 0; mi < 2; ++mi)
        af[mi] = *(const bf16x8*)&As[(wv * 32 + mi * 16 + lq) * 64 + ko];
#pragma unroll
      for (int ni = 0; ni < 4; ++ni)
        bfr[ni] = *(const bf16x8*)&Bs[(ni * 16 + lq) * 64 + ko];
#pragma unroll
      for (int mi = 0; mi < 2; ++mi)
#pragma unroll
        for (int ni = 0; ni < 4; ++ni)
          acc[mi][ni] = __builtin_amdgcn_mfma_f32_16x16x32_bf16(af[mi], bfr[ni], acc[mi][ni], 0, 0, 0);
    }
  }
#pragma unroll
  for (int mi = 0; mi < 2; ++mi)
#pragma unroll
    for (int ni = 0; ni < 4; ++ni) {
      int col = tileN + ni * 16 + lq;
#pragma unroll
      for (int rg = 0; rg < 4; ++rg) {
        int row = tileM + wv * 32 + mi * 16 + quad * 4 + rg;
        C[row * 1024 + col] = acc[mi][ni][rg] + bias[col];
      }
    }
}

// ---------------- fused synthesizer attention (single-writer) ---------------
// One block per (tt, bh); jt = 0..tt; balance swizzle tt=(31-x+y)&31 spreads
// co-resident tts. Direct bf16 y write (divide by L in-register). L via MFMA
// with ebj=exp(b2) fragment as B (bias folded: vt pre-scaled by exp(b2)).
__global__ __launch_bounds__(256, 4) void attn(
    const unsigned short* __restrict__ r, const unsigned short* __restrict__ w2t,
    const unsigned short* __restrict__ vt, const unsigned short* __restrict__ ebj,
    unsigned short* __restrict__ y) {
  __shared__ unsigned short W2s[2][64 * 64];
  __shared__ unsigned short Vs[2][64 * 64];
  __shared__ unsigned short Ps[4][16 * 64];

  const int tid = threadIdx.x;
  const int wv = tid >> 6, ln = tid & 63;
  const int quad = ln >> 4, lq = ln & 15;
  const int bh = blockIdx.y, b = bh >> 4, h = bh & 15;
  const int tt = (31 - blockIdx.x + blockIdx.y) & 31;  // LPT-ish balance
  const int rowL = ln >> 3;
  const int kc = (((ln & 7) ^ rowL) & 7) * 8;
  const int sx = lq & 7;
  const int ko0 = (quad ^ sx) * 8, ko1 = ((4 + quad) ^ sx) * 8;
  const int t0 = tt * 64;

  // R A-fragments for this t-tile (L2/L3-hot)
  bf16x8 ra0, ra1;
  {
    const unsigned short* base = r + (b * 2048 + t0 + wv * 16 + lq) * 1024 + h * 64 + quad * 8;
    ra0 = *(const bf16x8*)(base);
    ra1 = *(const bf16x8*)(base + 32);
  }

  f32x4 accY[4];
  f32x4 accL;
  const f32x4 zf = {0.f, 0.f, 0.f, 0.f};
#pragma unroll
  for (int nd = 0; nd < 4; ++nd) accY[nd] = zf;
  accL = zf;

  auto stage = [&](int jt, int bi) {
    int j0 = jt * 64;
#pragma unroll
    for (int l = 0; l < 2; ++l) {
      int row = l * 32 + wv * 8 + rowL;
      gload_lds16(w2t + (j0 + row) * 64 + kc, &W2s[bi][l * 2048 + wv * 512]);
      gload_lds16(vt + (h * 64 + row) * 4096 + b * 2048 + j0 + kc,
                  &Vs[bi][l * 2048 + wv * 512]);
    }
  };

  stage(0, 0);
  for (int jt = 0; jt <= tt; ++jt) {
    const int cb = jt & 1;
    __syncthreads();                 // staging(jt) landed; other buf free
    if (jt < tt) stage(jt + 1, cb ^ 1);
    const int j0 = jt * 64;

    // ebj B-fragments for the L-MFMA (k = kk*32 + quad*8 + i)
    bf16x8 eb0 = *(const bf16x8*)&ebj[j0 + quad * 8];
    bf16x8 eb1 = *(const bf16x8*)&ebj[j0 + 32 + quad * 8];
    // W2 B-fragments
    bf16x8 w2f0[4], w2f1[4];
#pragma unroll
    for (int ni = 0; ni < 4; ++ni) {
      w2f0[ni] = *(const bf16x8*)&W2s[cb][(ni * 16 + lq) * 64 + ko0];
      w2f1[ni] = *(const bf16x8*)&W2s[cb][(ni * 16 + lq) * 64 + ko1];
    }

    // S = R(16x64) @ W2^T -> C rows t=quad*4+rg, col j=lq (per ni)
    f32x4 sv[4] = {zf, zf, zf, zf};
#pragma unroll
    for (int ni = 0; ni < 4; ++ni) {
      sv[ni] = __builtin_amdgcn_mfma_f32_16x16x32_bf16(ra0, w2f0[ni], sv[ni], 0, 0, 0);
      sv[ni] = __builtin_amdgcn_mfma_f32_16x16x32_bf16(ra1, w2f1[ni], sv[ni], 0, 0, 0);
    }

    // exp (+ causal mask on diag tile), write P to LDS (A-layout, swizzled)
    const bool diag = (jt == tt);
#pragma unroll
    for (int ni = 0; ni < 4; ++ni) {
      int j = j0 + ni * 16 + lq;
#pragma unroll
      for (int rg = 0; rg < 4; ++rg) {
        float p = __expf(sv[ni][rg]);
        if (diag) {
          int t = t0 + wv * 16 + quad * 4 + rg;
          p = (j <= t) ? p : 0.f;
        }
        Ps[wv][(quad * 4 + rg) * 64 +
               (((ni * 2 + (lq >> 3)) ^ ((quad * 4 + rg) & 7)) * 8) + (lq & 7)] = f2bf_fast(p);
      }
    }

    // Y += P(16x64) @ V(64x64); L += P @ ebj
#pragma unroll
    for (int kk = 0; kk < 2; ++kk) {
      const int ko = kk ? ko1 : ko0;
      bf16x8 pa = *(const bf16x8*)&Ps[wv][lq * 64 + ko];
#pragma unroll
      for (int nd = 0; nd < 4; ++nd) {
        bf16x8 bb = *(const bf16x8*)&Vs[cb][(nd * 16 + lq) * 64 + ko];
        accY[nd] = __builtin_amdgcn_mfma_f32_16x16x32_bf16(pa, bb, accY[nd], 0, 0, 0);
      }
      accL = __builtin_amdgcn_mfma_f32_16x16x32_bf16(pa, kk ? eb1 : eb0, accL, 0, 0, 0);
    }
  }

  // epilogue: y = bf16(accY / L), direct store
  float inv[4];
#pragma unroll
  for (int rg = 0; rg < 4; ++rg) inv[rg] = __builtin_amdgcn_rcpf(accL[rg]);
#pragma unroll
  for (int nd = 0; nd < 4; ++nd)
#pragma unroll
    for (int rg = 0; rg < 4; ++rg) {
      int t = t0 + wv * 16 + quad * 4 + rg;
      y[(b * 2048 + t) * 1024 + h * 64 + nd * 16 + lq] = f2bf(accY[nd][rg] * inv[rg]);
    }
}

// ---------------- launch ----------------
extern "C" void kernel_launch(void* const* d_in, const int* in_sizes, int n_in,
                              void* d_out, int out_size, void* d_ws, size_t ws_size,
                              hipStream_t stream) {
  const float* x  = (const float*)d_in[0];
  const float* W1 = (const float*)d_in[1];
  const float* b1 = (const float*)d_in[2];
  const float* w2 = (const float*)d_in[3];
  const float* b2 = (const float*)d_in[4];
  const float* Wv = (const float*)d_in[5];
  const float* bv = (const float*)d_in[6];
  const float* Wp = (const float*)d_in[7];
  const float* bp = (const float*)d_in[8];

  unsigned short* ws  = (unsigned short*)d_ws;
  unsigned short* xb   = ws;                 // 4096x1024 bf16
  unsigned short* W1b  = ws + 4194304;       // 1024x1024
  unsigned short* Wvb  = ws + 5242880;       // 1024x1024
  unsigned short* Wpb  = ws + 6291456;       // 1024x1024
  unsigned short* w2t  = ws + 7340032;       // 2048x64
  unsigned short* rb   = ws + 7471104;       // 4096x1024
  unsigned short* vt   = ws + 11665408;      // 1024x4096
  unsigned short* yb   = ws + 15859712;      // 4096x1024 bf16
  unsigned short* ebjb = ws + 20054016;      // 2048 bf16

  prep<<<7298, 256, 0, stream>>>(x, W1, Wv, Wp, w2, b2, xb, W1b, Wvb, Wpb, w2t, ebjb);
  gemm_rv<<<512, 256, 0, stream>>>(xb, W1b, Wvb, b1, bv, b2, rb, vt);
  attn<<<dim3(32, 32), 256, 0, stream>>>(rb, w2t, vt, ebjb, yb);
  gemm_p<<<dim3(16, 32), 256, 0, stream>>>(yb, Wpb, bp, (float*)d_out);
}